// Round 10
// baseline (795.441 us; speedup 1.0000x reference)
//
#include <hip/hip_runtime.h>
#include <hip/hip_bf16.h>
#include <math.h>
#include <stdint.h>

// Problem constants
#define N_TOK   8192          // SL*BS
#define HS      1024
#define FFN     4096
#define NE      8
#define NA      16384         // N_TOK * TOPK
#define CAP     16384         // per-expert bucket capacity (worst case)
#define BMT     256           // M-tile rows
#define MAXT    72            // max total M-tiles: 16384/256 + 8
#define PERMSZ  16777216ULL   // NA * HS floats

typedef __attribute__((ext_vector_type(8))) short          bf16x8;
typedef __attribute__((ext_vector_type(4))) float          f32x4;
typedef __attribute__((ext_vector_type(4))) float          fvec4;
typedef __attribute__((ext_vector_type(4))) unsigned short usvec4;
typedef __attribute__((ext_vector_type(8))) unsigned short usvec8;

__device__ __forceinline__ void gl_lds16(const void* g, void* l) {
  __builtin_amdgcn_global_load_lds(
      (const __attribute__((address_space(1))) unsigned int*)g,
      (__attribute__((address_space(3))) unsigned int*)l,
      16, 0, 0);
}

__device__ __forceinline__ unsigned short f2bf(float f) {
  union { float f; unsigned int u; } v; v.f = f;
  unsigned int r = v.u + 0x7FFFu + ((v.u >> 16) & 1u);
  return (unsigned short)(r >> 16);
}

// ---------------- routing ----------------

__global__ void route_kernel(const int* __restrict__ idx, const float* __restrict__ wts,
                             int* __restrict__ counts, int* __restrict__ btok,
                             int* __restrict__ bslot, float* __restrict__ bw) {
  int a = blockIdx.x * 256 + threadIdx.x;
  if (a >= NA) return;
  int e = idx[a];
  int pos = atomicAdd(&counts[e], 1);
  btok[(size_t)e * CAP + pos]  = a >> 1;     // token id
  bslot[(size_t)e * CAP + pos] = a;          // destination slot in perm buffer
  bw[(size_t)e * CAP + pos]    = wts[a];
}

__global__ void build_tiles_kernel(int* __restrict__ counts, int2* __restrict__ table) {
  if (threadIdx.x == 0 && blockIdx.x == 0) {
    int nt = 0;
    for (int e = 0; e < NE; ++e) {
      int c = counts[e];
      int t = (c + BMT - 1) >> 8;
      for (int m = 0; m < t && nt < MAXT; ++m) table[nt++] = make_int2(e, m);
    }
    counts[8] = nt;
  }
}

// ---------------- packing kernels ----------------
// Packed operand layout: [... ][kt][row 0..255][64B], where the 64B row-chunk holds
// K-bytes (k&31)*2 with 16B-slot swizzle  slot ^= (row>>1)&3  baked in. A GEMM K-step
// then stages ONE contiguous 16KB chunk per operand (fully coalesced 1KB/wave bursts).

// gather + f32->bf16 + pack of x into xg[tile][kt 0..31][256][64B]
__global__ void pack_x_kernel(const float* __restrict__ x,
                              unsigned short* __restrict__ xg,
                              const int* __restrict__ btok,
                              const int* __restrict__ counts,
                              const int2* __restrict__ table) {
  int j = blockIdx.x, kt = blockIdx.y, row = threadIdx.x;
  int nt = counts[8];
  if (j >= nt) return;
  int2 te = table[j];
  int e = te.x, tm = te.y;
  int count = counts[e];
  int grow = tm * BMT + row;
  int tok = (grow < count) ? btok[(size_t)e * CAP + grow] : 0;
  const fvec4* src = (const fvec4*)(x + (size_t)tok * HS + kt * 32);  // 128B, one line
  char* dst = (char*)xg + ((size_t)j * 32 + kt) * 16384 + row * 64;
  int swz = (row >> 1) & 3;
#pragma unroll
  for (int s = 0; s < 4; ++s) {
    fvec4 v0 = src[2 * s], v1 = src[2 * s + 1];
    usvec8 o;
    o[0] = f2bf(v0[0]); o[1] = f2bf(v0[1]); o[2] = f2bf(v0[2]); o[3] = f2bf(v0[3]);
    o[4] = f2bf(v1[0]); o[5] = f2bf(v1[1]); o[6] = f2bf(v1[2]); o[7] = f2bf(v1[3]);
    *(usvec8*)(dst + ((s ^ swz) << 4)) = o;
  }
}

// in [E][R=K][C=N] f32 -> packed [E][n>>8][k>>5][n&255][64B swizzled] bf16
__global__ void pack_w_kernel(const float* __restrict__ in, unsigned short* __restrict__ out,
                              int R, int C) {
  __shared__ float t[64][65];
  int bc = blockIdx.x * 64, br = blockIdx.y * 64, e = blockIdx.z;
  const float* ine = in + (size_t)e * R * C;
  char* oute = (char*)out + (size_t)e * R * C * 2;
  int tx = threadIdx.x & 63, ty = threadIdx.x >> 6;   // ty in [0,4)
#pragma unroll
  for (int q = 0; q < 16; ++q) {
    int r = ty * 16 + q;
    t[r][tx] = ine[(size_t)(br + r) * C + bc + tx];
  }
  __syncthreads();
  int nkt = R / 32;
#pragma unroll
  for (int q = 0; q < 16; ++q) {
    int c = ty * 16 + q;
    int n = bc + c, k = br + tx;
    size_t addr = (((size_t)(n >> 8) * nkt + (k >> 5)) * 256 + (n & 255)) * 64
                + ((size_t)((((k & 31) >> 3) ^ ((n >> 1) & 3)) << 4)) + (k & 7) * 2;
    *(unsigned short*)(oute + addr) = f2bf(t[tx][c]);
  }
}

// ---- grouped GEMM: 256x256 tile, 8 waves (2Mx4N), wave 128x64, BK=32 ----
// 4 slabs x 32KB (A 16K | B 16K), 3-deep prefetch from PACKED chunks (contiguous 1KB
// per gl_lds). K-loop order (race-free by construction):
//   vmcnt(8): own step-hk loads landed (2 steps stay in flight, never drained)
//   s_barrier: ALL waves' iteration hk-1 ds_reads retired (lgkm waits precede MFMA use)
//   stage step hk+3 -> slab (hk-1)&3  [safe: only overwritten after that barrier]
//   ds_read slab hk&3 -> 32 MFMA (setprio)
// Persistent work-stealing, col-major units (B-slice L2 reuse, no tail).
template <int EPI, int NKT, int NUNIT>
__global__ __launch_bounds__(512, 1)
void moe_gemm(const unsigned short* __restrict__ Apk,   // xg (EPI=0) or hp (EPI=1)
              const unsigned short* __restrict__ Bpk,   // w1p / w2p
              unsigned short* __restrict__ hout,        // hp (EPI=0 output)
              float* __restrict__ perm,                 // EPI=1 output (2 K-half buffers)
              const int* __restrict__ bslot,
              const float* __restrict__ bw,
              const int* __restrict__ counts,
              const int2* __restrict__ table,
              int* __restrict__ ctr, int p0, int tc) {
  __shared__ char lds[131072];
  __shared__ int s_u;

  int tid = threadIdx.x, wid = tid >> 6, lane = tid & 63;
  int wm = wid >> 2, wn = wid & 3;
  int l15 = lane & 15, l16 = lane >> 4;
  int nt = counts[8];

  int swz16 = (l16 ^ ((l15 >> 1) & 3)) << 4;
  int offA0 = (wm * 128 + l15) * 64 + swz16;            // frag stride 1024B
  int offB0 = 16384 + (wn * 64 + l15) * 64 + swz16;
  int cbase[4];
#pragma unroll
  for (int q = 0; q < 4; ++q) cbase[q] = (wid * 4 + q) * 1024;

  for (;;) {
    __syncthreads();                       // LDS + s_u safe for reuse
    if (tid == 0) s_u = atomicAdd(ctr, 1);
    __syncthreads();
    int u = s_u;
    if (u >= NUNIT) return;

    int j, col, kq;
    if (EPI == 0) { col = u / MAXT; j = u - col * MAXT; kq = 0; }
    else { int g = u / MAXT; j = u - g * MAXT; col = g & 3; kq = g >> 2; }
    if (j >= nt || j < p0 || j >= p0 + tc) continue;
    int2 te = table[j];
    int e = te.x, tm = te.y;
    int count = counts[e];
    int slotb = j - p0;

    const char* Asrc; const char* Bsrc;
    if (EPI == 0) {
      Asrc = (const char*)Apk + (size_t)j * (32 * 16384);
      Bsrc = (const char*)Bpk + (size_t)e * 8388608 + (size_t)col * (32 * 16384);
    } else {
      Asrc = (const char*)Apk + (size_t)slotb * (128 * 16384) + (size_t)kq * (64 * 16384);
      Bsrc = (const char*)Bpk + (size_t)e * 8388608 + (size_t)col * (128 * 16384)
           + (size_t)kq * (64 * 16384);
    }
    const char* csrc[4];
#pragma unroll
    for (int q = 0; q < 4; ++q) {
      int c = wid * 4 + q;
      csrc[q] = (c < 16 ? Asrc + c * 1024 : Bsrc + (c - 16) * 1024) + lane * 16;
    }

    f32x4 acc[8][4] = {};

    // prologue: stage K-steps 0,1,2 -> slabs 0,1,2 (12 loads/wave in flight)
#pragma unroll
    for (int s = 0; s < 3; ++s)
#pragma unroll
      for (int q = 0; q < 4; ++q)
        gl_lds16(csrc[q] + (size_t)s * 16384, lds + s * 32768 + cbase[q]);

    for (int hk = 0; hk < NKT; ++hk) {
      asm volatile("s_waitcnt vmcnt(8)" ::: "memory");   // own step-hk loads landed
      __builtin_amdgcn_sched_barrier(0);
      __builtin_amdgcn_s_barrier();   // all waves: step hk visible AND hk-1 reads retired
      __builtin_amdgcn_sched_barrier(0);

      int hs = hk + 3; if (hs >= NKT) hs -= NKT;   // wrap re-stage keeps vmcnt uniform
      char* db = lds + (hs & 3) * 32768;           // == slab (hk-1)&3 in steady state
#pragma unroll
      for (int q = 0; q < 4; ++q)
        gl_lds16(csrc[q] + (size_t)hs * 16384, db + cbase[q]);

      const char* rbuf = lds + (hk & 3) * 32768;
      bf16x8 a[8], b[4];
#pragma unroll
      for (int n = 0; n < 4; ++n) b[n] = *(const bf16x8*)(rbuf + offB0 + n * 1024);
#pragma unroll
      for (int i = 0; i < 8; ++i) a[i] = *(const bf16x8*)(rbuf + offA0 + i * 1024);
      __builtin_amdgcn_s_setprio(1);
#pragma unroll
      for (int i = 0; i < 8; ++i)
#pragma unroll
        for (int n = 0; n < 4; ++n)
          acc[i][n] = __builtin_amdgcn_mfma_f32_16x16x32_bf16(a[i], b[n], acc[i][n], 0, 0, 0);
      __builtin_amdgcn_s_setprio(0);
      __builtin_amdgcn_sched_barrier(0);
    }
    asm volatile("s_waitcnt vmcnt(0)" ::: "memory");  // drain wrap re-stages
    __builtin_amdgcn_s_barrier();                     // loop fully done on all waves

    // epilogue: per-wave LDS repack (8KB) -> vector stores
    char* wlds = lds + wid * 8192;         // 32 rows x 256B (64 f32)
#pragma unroll
    for (int p = 0; p < 4; ++p) {          // 4 passes x 32 rows = wave's 128 rows
#pragma unroll
      for (int ii = 0; ii < 2; ++ii) {
        int i = p * 2 + ii;
#pragma unroll
        for (int n = 0; n < 4; ++n) {
          int waddr = (ii * 16 + l16 * 4) * 256 + (n * 16 + l15) * 4;
#pragma unroll
          for (int rr = 0; rr < 4; ++rr)
            *(float*)(wlds + waddr + rr * 256) = acc[i][n][rr];
        }
      }
      asm volatile("s_waitcnt lgkmcnt(0)" ::: "memory");
      __builtin_amdgcn_sched_barrier(0);
#pragma unroll
      for (int rd = 0; rd < 8; ++rd) {
        int row = rd * 4 + l16;            // 0..31
        f32x4 v = *(const f32x4*)(wlds + row * 256 + l15 * 16);
        int colg = col * 256 + wn * 64 + l15 * 4;
        int hrow = wm * 128 + p * 32 + row;
        if (EPI == 0) {
          usvec4 o;
#pragma unroll
          for (int z = 0; z < 4; ++z) {
            float vv = v[z];
            float x2 = vv * vv;
            float u2 = 1.5957691216057308f * vv * fmaf(0.044715f, x2, 1.0f);
            u2 = fminf(fmaxf(u2, -30.f), 30.f);
            float ee = __expf(u2);
            o[z] = f2bf(vv * __fdividef(ee, ee + 1.0f));
          }
          // store into PACKED hp: [slotb][kt=colg>>5][hrow][64B swizzled]
          int kt = colg >> 5;
          int slotc = ((colg & 31) >> 3) ^ ((hrow >> 1) & 3);
          char* hpc = (char*)hout + (size_t)slotb * 2097152 + (size_t)kt * 16384
                    + hrow * 64 + (slotc << 4) + (colg & 7) * 2;
          *(usvec4*)hpc = o;               // 8B: 4 bf16
        } else {
          int grow = tm * BMT + hrow;
          if (grow < count) {
            int s = bslot[(size_t)e * CAP + grow];
            float wgt = bw[(size_t)e * CAP + grow];
            fvec4 o;
#pragma unroll
            for (int z = 0; z < 4; ++z) o[z] = wgt * v[z];
            *(fvec4*)(perm + (size_t)kq * PERMSZ + (size_t)s * HS + colg) = o;
          }
        }
      }
      __builtin_amdgcn_sched_barrier(0);
    }
  }
}

// ---------------- combine: out[t] = sum over 2 slots x 2 K-halves ----------------
__global__ void combine_kernel(const fvec4* __restrict__ perm, fvec4* __restrict__ out, int n4) {
  int i = blockIdx.x * 256 + threadIdx.x;
  if (i >= n4) return;
  int t = i >> 8;            // HS/4 = 256 fvec4 per row
  int c = i & 255;
  const fvec4* p0 = perm;
  const fvec4* p1 = perm + PERMSZ / 4;
  size_t r0 = (size_t)(2 * t) * 256 + c;
  size_t r1 = (size_t)(2 * t + 1) * 256 + c;
  out[i] = (p0[r0] + p1[r0]) + (p0[r1] + p1[r1]);
}

// ---------------- host ----------------

extern "C" void kernel_launch(void* const* d_in, const int* in_sizes, int n_in,
                              void* d_out, int out_size, void* d_ws, size_t ws_size,
                              hipStream_t stream) {
  const float* x   = (const float*)d_in[0];
  const float* ew  = (const float*)d_in[1];
  // d_in[2] = scores (unused by reference output)
  const float* w1  = (const float*)d_in[3];
  const float* w2  = (const float*)d_in[4];
  const int*   eix = (const int*)d_in[5];

  char* ws = (char*)d_ws;
  const size_t o_w1p    = 0;                       //  67,108,864
  const size_t o_w2p    = 67108864ULL;             //  67,108,864
  const size_t o_xg     = 134217728ULL;            //  37,748,736
  const size_t o_btok   = 171966464ULL;            //     524,288
  const size_t o_bslot  = 172490752ULL;            //     524,288
  const size_t o_bw     = 173015040ULL;            //     524,288
  const size_t o_counts = 173539328ULL;            //         256
  const size_t o_table  = 173539584ULL;            //       2,048
  const size_t o_ctr    = 173541632ULL;            //       2,048
  const size_t o_perm   = 173543680ULL;            // 2 x 67,108,864
  const size_t o_hp     = 307761408ULL;            // up to 150,994,944

  unsigned short* w1p = (unsigned short*)(ws + o_w1p);
  unsigned short* w2p = (unsigned short*)(ws + o_w2p);
  unsigned short* xg  = (unsigned short*)(ws + o_xg);
  int*   btok   = (int*)(ws + o_btok);
  int*   bslot  = (int*)(ws + o_bslot);
  float* bw     = (float*)(ws + o_bw);
  int*   counts = (int*)(ws + o_counts);
  int2*  table  = (int2*)(ws + o_table);
  int*   ctrs   = (int*)(ws + o_ctr);
  float* perm   = (float*)(ws + o_perm);
  unsigned short* hp = (unsigned short*)(ws + o_hp);

  // h-window chunking if workspace is small (2MB per M-tile)
  long long havail = (long long)ws_size - (long long)o_hp;
  int tc = (int)(havail / 2097152LL);
  if (tc < 1) tc = 1;
  if (tc > MAXT) tc = MAXT;
  int npass = (MAXT + tc - 1) / tc;
  if (npass > 128) npass = 128;

  hipMemsetAsync(counts, 0, 256, stream);
  hipMemsetAsync(ctrs, 0, 2048, stream);

  route_kernel<<<(NA + 255) / 256, 256, 0, stream>>>(eix, ew, counts, btok, bslot, bw);
  build_tiles_kernel<<<1, 64, 0, stream>>>(counts, table);

  pack_x_kernel<<<dim3(MAXT, 32), 256, 0, stream>>>(x, xg, btok, counts, table);
  pack_w_kernel<<<dim3(FFN / 64, HS / 64, NE), 256, 0, stream>>>(w1, w1p, HS, FFN);
  pack_w_kernel<<<dim3(HS / 64, FFN / 64, NE), 256, 0, stream>>>(w2, w2p, FFN, HS);

  for (int p = 0; p < npass; ++p) {
    // GEMM1: units = 16 cols x 72 tiles = 1152, K=1024 (NKT=32)
    moe_gemm<0, 32, 16 * MAXT><<<dim3(256), 512, 0, stream>>>(
        xg, w1p, hp, perm, bslot, bw, counts, table, &ctrs[p * 2 + 0], p * tc, tc);
    // GEMM2: units = 2 kq x 4 cols x 72 tiles = 576, K=2048 each (NKT=64)
    moe_gemm<1, 64, 8 * MAXT><<<dim3(256), 512, 0, stream>>>(
        hp, w2p, hp, perm, bslot, bw, counts, table, &ctrs[p * 2 + 1], p * tc, tc);
  }

  combine_kernel<<<(N_TOK * HS / 4 + 255) / 256, 256, 0, stream>>>(
      (const fvec4*)perm, (fvec4*)d_out, N_TOK * HS / 4);
}

// Round 11
// 619.404 us; speedup vs baseline: 1.2842x; 1.2842x over previous
//
#include <hip/hip_runtime.h>
#include <hip/hip_bf16.h>
#include <math.h>
#include <stdint.h>

// Problem constants
#define N_TOK   8192          // SL*BS
#define HS      1024
#define FFN     4096
#define NE      8
#define NA      16384         // N_TOK * TOPK
#define CAP     16384         // per-expert bucket capacity (worst case)
#define BM      256
#define MAXT    72            // max total M-tiles: 16384/256 + 8

typedef __attribute__((ext_vector_type(8))) short          bf16x8;
typedef __attribute__((ext_vector_type(4))) float          f32x4;
typedef __attribute__((ext_vector_type(4))) float          fvec4;
typedef __attribute__((ext_vector_type(4))) unsigned short usvec4;

__device__ __forceinline__ void gl_lds16(const void* g, void* l) {
  __builtin_amdgcn_global_load_lds(
      (const __attribute__((address_space(1))) unsigned int*)g,
      (__attribute__((address_space(3))) unsigned int*)l,
      16, 0, 0);
}

__device__ __forceinline__ unsigned short f2bf(float f) {
  union { float f; unsigned int u; } v; v.f = f;
  unsigned int r = v.u + 0x7FFFu + ((v.u >> 16) & 1u);
  return (unsigned short)(r >> 16);
}

// ---------------- conversion kernels ----------------

__global__ void cvt_x_kernel(const fvec4* __restrict__ in, unsigned short* __restrict__ out, int n4) {
  int i = blockIdx.x * 256 + threadIdx.x;
  if (i >= n4) return;
  fvec4 v = in[i];
  usvec4 o;
  o[0] = f2bf(v[0]); o[1] = f2bf(v[1]); o[2] = f2bf(v[2]); o[3] = f2bf(v[3]);
  *(usvec4*)(out + (size_t)i * 4) = o;
}

// in [E][R][C] f32 -> out [E][C][R] bf16 (K-contiguous B^T layout for GEMM)
__global__ void tpose_cvt_kernel(const float* __restrict__ in, unsigned short* __restrict__ out,
                                 int R, int C) {
  __shared__ float t[64][65];
  int bc = blockIdx.x * 64, br = blockIdx.y * 64, e = blockIdx.z;
  const float* ine = in + (size_t)e * R * C;
  unsigned short* oute = out + (size_t)e * R * C;
  int tx = threadIdx.x & 63, ty = threadIdx.x >> 6;   // ty in [0,4)
#pragma unroll
  for (int q = 0; q < 16; ++q) {
    int r = ty * 16 + q;
    t[r][tx] = ine[(size_t)(br + r) * C + bc + tx];
  }
  __syncthreads();
#pragma unroll
  for (int q = 0; q < 16; ++q) {
    int c = ty * 16 + q;
    oute[(size_t)(bc + c) * R + br + tx] = f2bf(t[tx][c]);
  }
}

// ---------------- routing ----------------

__global__ void route_kernel(const int* __restrict__ idx, const float* __restrict__ wts,
                             int* __restrict__ counts, int* __restrict__ btok,
                             int* __restrict__ bslot, float* __restrict__ bw) {
  int a = blockIdx.x * 256 + threadIdx.x;
  if (a >= NA) return;
  int e = idx[a];
  int pos = atomicAdd(&counts[e], 1);
  btok[(size_t)e * CAP + pos]  = a >> 1;     // token id
  bslot[(size_t)e * CAP + pos] = a;          // assignment index
  bw[(size_t)e * CAP + pos]    = wts[a];
}

__global__ void build_tiles_kernel(int* __restrict__ counts, int2* __restrict__ table) {
  if (threadIdx.x == 0 && blockIdx.x == 0) {
    int nt = 0;
    for (int e = 0; e < NE; ++e) {
      int c = counts[e];
      int t = (c + BM - 1) >> 8;
      for (int m = 0; m < t && nt < MAXT; ++m) table[nt++] = make_int2(e, m);
    }
    counts[8] = nt;
  }
}

// ---------------- grouped GEMM, counted-vmcnt triple-buffer pipeline (R3-proven) ----------------
// Tile BM=256 x BN_=128, BK=32, 4 waves, per-wave 128x64 (acc[8][4]).
// LDS: 3 buffers of [A 256x32 | B 128x32] bf16, XOR-swizzled (k_byte ^= ((row>>1)&3)<<4).
// Schedule per K-step: vmcnt(6) -> s_barrier -> stage kt+2 -> grouped ds_read/MFMA
// (compiler counted lgkm waits) -> setprio. Tile-clustered XCD decode (A-panel L2 reuse).
// EPI=0: h = gelu(gather(x)@w1).  EPI=1: atomicAdd(out[token], wgt * (h@w2)) - no combine.
template <int NWN, int EPI, int KDIM, int NOUT>
__global__ __launch_bounds__(NWN * 128, 2)
void moe_gemm(const unsigned short* __restrict__ Ab,   // xb (EPI=0) or h (EPI=1)
              const unsigned short* __restrict__ Bb,   // w1T / w2T, [E][N][K] bf16
              unsigned short* __restrict__ hout,       // EPI=0 output
              float* __restrict__ outp,                // EPI=1 output (d_out, zeroed)
              const int* __restrict__ btok,
              const int* __restrict__ bslot,
              const float* __restrict__ bw,
              const int* __restrict__ counts,
              const int2* __restrict__ table,
              int p0, int tc) {
  constexpr int NWAVES = 2 * NWN;
  constexpr int BN_ = NWN * 64;
  constexpr int NBLK = NOUT / BN_;         // N-blocks per tile (32 for g1, 8 for g2)
  constexpr int NCH = 16 + BN_ / 16;       // 1KB staging chunks per K-tile
  constexpr int CPW = NCH / NWAVES;        // gl_lds instrs per wave per K-tile
  constexpr int BUFSZ = 16384 + BN_ * 64;  // bytes per buffer
  constexpr int NT = KDIM / 32;

  __shared__ char lds[3 * BUFSZ];

  // Tile-clustered decode (R3, best measured): tile j on XCD j&7; its NBLK
  // consumer blocks are consecutive slots on that XCD -> A-panel L2 reuse.
  int bid = blockIdx.x;
  int xcd = bid & 7, slot = bid >> 3;
  int j = xcd + 8 * (slot / NBLK);
  int bn0 = (slot % NBLK) * BN_;

  int nt = counts[8];
  if (j < p0 || j >= p0 + tc || j >= nt) return;
  int2 te = table[j];
  int e = te.x, tm = te.y;
  int count = counts[e];
  int slotb = j - p0;

  int tid = threadIdx.x;
  int wave = tid >> 6, lane = tid & 63;
  int wm = wave / NWN, wn = wave % NWN;

  const unsigned short* Be = Bb + (size_t)e * ((size_t)FFN * HS);

  // ---- staging setup (pre-swizzled global sources, wave-uniform LDS dests) ----
  const char* src[CPW];
  int dst[CPW];
#pragma unroll
  for (int q = 0; q < CPW; ++q) {
    int c = wave * CPW + q;
    int rr = (c < 16 ? c * 16 : (c - 16) * 16) + (lane >> 2);
    int klog = ((lane & 3) * 16) ^ (((rr >> 1) & 3) << 4);
    if (c < 16) {          // A chunk
      dst[q] = c * 1024;
      if (EPI == 0) {
        int grow = tm * BM + rr;
        int tok = (grow < count) ? btok[(size_t)e * CAP + grow] : 0;
        src[q] = (const char*)(Ab + (size_t)tok * KDIM) + klog;
      } else {
        src[q] = (const char*)(Ab + ((size_t)slotb * BM + rr) * KDIM) + klog;
      }
    } else {               // B chunk
      dst[q] = 16384 + (c - 16) * 1024;
      src[q] = (const char*)(Be + (size_t)(bn0 + rr) * KDIM) + klog;
    }
  }

  // ---- fragment read offsets (swizzled) ----
  int rA = wm * 128 + (lane & 15);
  int rB = wn * 64 + (lane & 15);
  int ks = (lane >> 4) * 16;
  int offA0 = rA * 64 + (ks ^ (((rA >> 1) & 3) << 4));
  int offB0 = 16384 + rB * 64 + (ks ^ (((rB >> 1) & 3) << 4));

  f32x4 acc[8][4] = {};

  // ---- prologue: stage kt0 -> buf0, kt1 -> buf1 ----
#pragma unroll
  for (int q = 0; q < CPW; ++q) gl_lds16(src[q], lds + dst[q]);
#pragma unroll
  for (int q = 0; q < CPW; ++q) gl_lds16(src[q] + 64, lds + BUFSZ + dst[q]);

  int bi = 0;
  for (int t = 0; t < NT; ++t) {
    // own kt-t loads landed (kt t+1's CPW may stay in flight)
    if constexpr (CPW == 4) asm volatile("s_waitcnt vmcnt(4)" ::: "memory");
    else                    asm volatile("s_waitcnt vmcnt(6)" ::: "memory");
    __builtin_amdgcn_sched_barrier(0);
    __builtin_amdgcn_s_barrier();   // all waves: kt t visible; buf (t+2)%3 free
    __builtin_amdgcn_sched_barrier(0);

    int kt2 = t + 2; if (kt2 >= NT) kt2 -= NT;   // wrap re-stage keeps vmcnt uniform
    int bi2 = bi + 2; if (bi2 >= 3) bi2 -= 3;
    char* db = lds + bi2 * BUFSZ;
#pragma unroll
    for (int q = 0; q < CPW; ++q)
      gl_lds16(src[q] + (size_t)kt2 * 64, db + dst[q]);

    const char* rbuf = lds + bi * BUFSZ;
    bf16x8 a[8], b[4];
    // read group 0: all B frags + a0,a1
    b[0] = *(const bf16x8*)(rbuf + offB0);
    b[1] = *(const bf16x8*)(rbuf + offB0 + 1024);
    b[2] = *(const bf16x8*)(rbuf + offB0 + 2048);
    b[3] = *(const bf16x8*)(rbuf + offB0 + 3072);
    a[0] = *(const bf16x8*)(rbuf + offA0);
    a[1] = *(const bf16x8*)(rbuf + offA0 + 1024);
    __builtin_amdgcn_sched_barrier(0);
    a[2] = *(const bf16x8*)(rbuf + offA0 + 2048);
    a[3] = *(const bf16x8*)(rbuf + offA0 + 3072);
    __builtin_amdgcn_sched_barrier(0);
    a[4] = *(const bf16x8*)(rbuf + offA0 + 4096);
    a[5] = *(const bf16x8*)(rbuf + offA0 + 5120);
    __builtin_amdgcn_sched_barrier(0);
    a[6] = *(const bf16x8*)(rbuf + offA0 + 6144);
    a[7] = *(const bf16x8*)(rbuf + offA0 + 7168);
    __builtin_amdgcn_sched_barrier(0);
    // MFMA groups on disjoint accumulators; compiler emits counted lgkm waits
    __builtin_amdgcn_s_setprio(1);
#pragma unroll
    for (int g = 0; g < 4; ++g) {
#pragma unroll
      for (int i = 2 * g; i < 2 * g + 2; ++i)
#pragma unroll
        for (int n = 0; n < 4; ++n)
          acc[i][n] = __builtin_amdgcn_mfma_f32_16x16x32_bf16(a[i], b[n], acc[i][n], 0, 0, 0);
      __builtin_amdgcn_sched_barrier(0);
    }
    __builtin_amdgcn_s_setprio(0);
    ++bi; if (bi >= 3) bi = 0;
  }

  // ---- epilogue ----
  if (EPI == 0) {
    size_t hb = (size_t)slotb * BM;
#pragma unroll
    for (int i = 0; i < 8; ++i) {
      int row = wm * 128 + i * 16 + ((lane >> 4) << 2);
#pragma unroll
      for (int n = 0; n < 4; ++n) {
        int col = bn0 + wn * 64 + n * 16 + (lane & 15);
#pragma unroll
        for (int r = 0; r < 4; ++r) {
          float v = acc[i][n][r];
          // gelu(v) = v * sigmoid(2u), u = 0.79788456 v (1 + 0.044715 v^2)
          float x2 = v * v;
          float u2 = 1.5957691216057308f * v * fmaf(0.044715f, x2, 1.0f);  // 2u
          u2 = fminf(fmaxf(u2, -30.f), 30.f);
          float ee = __expf(u2);
          float g = v * __fdividef(ee, ee + 1.0f);
          hout[(hb + row + r) * FFN + col] = f2bf(g);
        }
      }
    }
  } else {
#pragma unroll
    for (int i = 0; i < 8; ++i) {
      int rowb = wm * 128 + i * 16 + ((lane >> 4) << 2);
#pragma unroll
      for (int r = 0; r < 4; ++r) {
        int grow = tm * BM + rowb + r;
        if (grow < count) {
          int s = bslot[(size_t)e * CAP + grow];
          float wgt = bw[(size_t)e * CAP + grow];
          int tok = s >> 1;
#pragma unroll
          for (int n = 0; n < 4; ++n) {
            int col = bn0 + wn * 64 + n * 16 + (lane & 15);
            atomicAdd(&outp[(size_t)tok * HS + col], wgt * acc[i][n][r]);
          }
        }
      }
    }
  }
}

// ---------------- host ----------------

extern "C" void kernel_launch(void* const* d_in, const int* in_sizes, int n_in,
                              void* d_out, int out_size, void* d_ws, size_t ws_size,
                              hipStream_t stream) {
  const float* x   = (const float*)d_in[0];
  const float* ew  = (const float*)d_in[1];
  // d_in[2] = scores (unused by reference output)
  const float* w1  = (const float*)d_in[3];
  const float* w2  = (const float*)d_in[4];
  const int*   eix = (const int*)d_in[5];

  char* ws = (char*)d_ws;
  const size_t o_w1T    = 0;                       // 67,108,864
  const size_t o_w2T    = 67108864ULL;             // 67,108,864
  const size_t o_xb     = 134217728ULL;            // 16,777,216
  const size_t o_btok   = 150994944ULL;            // 524,288
  const size_t o_bslot  = 151519232ULL;            // 524,288
  const size_t o_bw     = 152043520ULL;            // 524,288
  const size_t o_counts = 152567808ULL;            // 256
  const size_t o_table  = 152568064ULL;            // 1,280
  const size_t o_h      = 152569344ULL;            // up to 150,994,944

  unsigned short* w1T = (unsigned short*)(ws + o_w1T);
  unsigned short* w2T = (unsigned short*)(ws + o_w2T);
  unsigned short* xb  = (unsigned short*)(ws + o_xb);
  int*   btok   = (int*)(ws + o_btok);
  int*   bslot  = (int*)(ws + o_bslot);
  float* bw     = (float*)(ws + o_bw);
  int*   counts = (int*)(ws + o_counts);
  int2*  table  = (int2*)(ws + o_table);
  unsigned short* hbuf = (unsigned short*)(ws + o_h);
  float* outp = (float*)d_out;

  // h-buffer chunking if workspace is small
  long long havail = (long long)ws_size - (long long)o_h;
  long long tile_bytes = (long long)BM * FFN * 2;   // 2 MB per M-tile
  int tc = (int)(havail / tile_bytes);
  if (tc < 1) tc = 1;
  if (tc > MAXT) tc = MAXT;
  int npass = (MAXT + tc - 1) / tc;

  hipMemsetAsync(counts, 0, 256, stream);
  hipMemsetAsync(d_out, 0, (size_t)out_size * 4, stream);  // gemm2 accumulates into out

  cvt_x_kernel<<<(N_TOK * HS / 4 + 255) / 256, 256, 0, stream>>>(
      (const fvec4*)x, xb, N_TOK * HS / 4);
  tpose_cvt_kernel<<<dim3(FFN / 64, HS / 64, NE), 256, 0, stream>>>(w1, w1T, HS, FFN);
  tpose_cvt_kernel<<<dim3(HS / 64, FFN / 64, NE), 256, 0, stream>>>(w2, w2T, FFN, HS);

  route_kernel<<<(NA + 255) / 256, 256, 0, stream>>>(eix, ew, counts, btok, bslot, bw);
  build_tiles_kernel<<<1, 64, 0, stream>>>(counts, table);

  for (int p = 0; p < npass; ++p) {
    // GEMM1: 256x128 tile, 4 waves, K=HS, N=FFN -> 32 N-blocks * 72 tiles = 2304
    moe_gemm<2, 0, HS, FFN><<<dim3(MAXT * 32), 256, 0, stream>>>(
        xb, w1T, hbuf, outp, btok, bslot, bw, counts, table, p * tc, tc);
    // GEMM2: 256x128 tile, 4 waves, K=FFN, N=HS -> 8 N-blocks * 72 tiles = 576
    moe_gemm<2, 1, FFN, HS><<<dim3(MAXT * 8), 256, 0, stream>>>(
        hbuf, w2T, hbuf, outp, btok, bslot, bw, counts, table, p * tc, tc);
  }
}